// Round 1
// baseline (1058.183 us; speedup 1.0000x reference)
//
#include <hip/hip_runtime.h>

typedef _Float16 half8 __attribute__((ext_vector_type(8)));
typedef float floatx4 __attribute__((ext_vector_type(4)));

#define BATCH 131072
#define S_DIM 376
#define H1D 400
#define H2D 300
#define ODIM 255
#define NACT 17

#define SP 384      // padded K for layer 1
#define K2P 416     // padded K for layer 2 (weights)
#define H2P 320     // padded h2 width / K for layer 3
#define OP 256      // padded output width

// ws offsets in halfs
#define W1HI 0
#define W1LO 153600
#define W2HI 307200
#define W2LO 433664
#define W3HI 560128
#define W3LO 642048

#define MFMA16(a, b, c) __builtin_amdgcn_mfma_f32_16x16x32_f16(a, b, c, 0, 0, 0)

// ---------------- prep: split fp32 weights into (hi,lo) fp16 planes, transposed [n][k], zero-padded ----------------
__global__ __launch_bounds__(256) void prep_kernel(const float* __restrict__ W1,
                                                   const float* __restrict__ W2,
                                                   const float* __restrict__ W3,
                                                   _Float16* __restrict__ ws) {
  int idx = blockIdx.x * 256 + threadIdx.x;
  float v;
  int hioff, looff;
  if (idx < 153600) {                 // W1p: [400][384]
    int n = idx / 384, k = idx - n * 384;
    v = (k < S_DIM) ? W1[k * H1D + n] : 0.f;
    hioff = W1HI + idx; looff = W1LO + idx;
  } else if (idx < 280064) {          // W2p: [304][416]
    int e = idx - 153600;
    int n = e / 416, k = e - n * 416;
    v = (k < H1D && n < H2D) ? W2[k * H2D + n] : 0.f;
    hioff = W2HI + e; looff = W2LO + e;
  } else if (idx < 361984) {          // W3p: [256][320]
    int e = idx - 280064;
    int n = e / 320, k = e - n * 320;
    v = (k < H2D && n < ODIM) ? W3[k * ODIM + n] : 0.f;
    hioff = W3HI + e; looff = W3LO + e;
  } else {
    return;
  }
  _Float16 hi = (_Float16)v;
  ws[hioff] = hi;
  ws[looff] = (_Float16)(v - (float)hi);
}

// ---------------- fused actor kernel ----------------
__global__ __launch_bounds__(256, 1) void actor_kernel(const float* __restrict__ state,
                                                       const float* __restrict__ eps,
                                                       const float* __restrict__ b1,
                                                       const float* __restrict__ b2,
                                                       const float* __restrict__ b3,
                                                       const _Float16* __restrict__ wsp,
                                                       float* __restrict__ out) {
  extern __shared__ char smem[];
  // LDS layout (bytes): Wbuf [400][32]x2 = 51200 | Abuf [64][32]x2 = 8192 | H region 102400
  _Float16* Whi = (_Float16*)smem;
  _Float16* Wlo = Whi + 400 * 32;
  _Float16* Ahi = (_Float16*)(smem + 51200);
  _Float16* Alo = Ahi + 64 * 32;
  char* Hb = smem + 59392;
  _Float16* H1hi = (_Float16*)Hb;        // [64][400]
  _Float16* H1lo = H1hi + 64 * 400;

  const int t = threadIdx.x;
  const int wave = t >> 6;
  const int lane = t & 63;
  const int q = lane >> 4;
  const int m = lane & 15;
  const long rowbase = (long)blockIdx.x * 64;

  half8 zf;
#pragma unroll
  for (int j = 0; j < 8; ++j) zf[j] = (_Float16)0.f;

  // ================= Layer 1: h1 = relu(state @ W1 + b1) =================
  floatx4 acc[25];
#pragma unroll
  for (int i = 0; i < 25; ++i) {
    acc[i][0] = 0.f; acc[i][1] = 0.f; acc[i][2] = 0.f; acc[i][3] = 0.f;
  }

  for (int kc = 0; kc < 12; ++kc) {
    __syncthreads();
    // ---- stage A (state chunk, split) ----
    {
      const int row = t >> 2, qq = t & 3;
      const int c0 = kc * 32 + qq * 8;
      float v[8];
      if (c0 + 8 <= S_DIM) {
        const float4* sp = (const float4*)(state + (rowbase + row) * S_DIM + c0);
        float4 x0 = sp[0], x1 = sp[1];
        v[0] = x0.x; v[1] = x0.y; v[2] = x0.z; v[3] = x0.w;
        v[4] = x1.x; v[5] = x1.y; v[6] = x1.z; v[7] = x1.w;
      } else {
#pragma unroll
        for (int j = 0; j < 8; ++j) v[j] = 0.f;
      }
      half8 h, l;
#pragma unroll
      for (int j = 0; j < 8; ++j) {
        _Float16 hi = (_Float16)v[j];
        h[j] = hi;
        l[j] = (_Float16)(v[j] - (float)hi);
      }
      *(half8*)(Ahi + row * 32 + qq * 8) = h;
      *(half8*)(Alo + row * 32 + qq * 8) = l;
    }
    // ---- stage W1 chunk: 400 rows x 32 k, both planes = 3200 x 16B ----
#pragma unroll
    for (int j = 0; j < 13; ++j) {
      int idx = t + j * 256;
      if (idx < 3200) {
        bool lo = idx >= 1600;
        int e = lo ? idx - 1600 : idx;
        int n = e >> 2, part = e & 3;
        const _Float16* src = wsp + (lo ? W1LO : W1HI) + n * SP + kc * 32 + part * 8;
        _Float16* dst = (lo ? Wlo : Whi) + n * 32 + part * 8;
        *(half8*)dst = *(const half8*)src;
      }
    }
    __syncthreads();
    const half8 ah = *(const half8*)(Ahi + (wave * 16 + m) * 32 + q * 8);
    const half8 al = *(const half8*)(Alo + (wave * 16 + m) * 32 + q * 8);
#pragma unroll
    for (int nt = 0; nt < 25; ++nt) {
      const half8 bh = *(const half8*)(Whi + (nt * 16 + m) * 32 + q * 8);
      const half8 bl = *(const half8*)(Wlo + (nt * 16 + m) * 32 + q * 8);
      acc[nt] = MFMA16(ah, bh, acc[nt]);
      acc[nt] = MFMA16(ah, bl, acc[nt]);
      acc[nt] = MFMA16(al, bh, acc[nt]);
    }
  }
  // h1 writeback (bias + relu + split). Visible to all waves via layer-2 loop barriers.
#pragma unroll
  for (int nt = 0; nt < 25; ++nt) {
    const int col = nt * 16 + m;
    const float bias = b1[col];
#pragma unroll
    for (int r = 0; r < 4; ++r) {
      const int row = wave * 16 + q * 4 + r;
      float v = fmaxf(acc[nt][r] + bias, 0.f);
      _Float16 hi = (_Float16)v;
      H1hi[row * 400 + col] = hi;
      H1lo[row * 400 + col] = (_Float16)(v - (float)hi);
    }
  }

  // ================= Layer 2: h2 = relu(h1 @ W2 + b2) =================
  floatx4 acc2[19];
#pragma unroll
  for (int i = 0; i < 19; ++i) {
    acc2[i][0] = 0.f; acc2[i][1] = 0.f; acc2[i][2] = 0.f; acc2[i][3] = 0.f;
  }
  for (int kc = 0; kc < 13; ++kc) {
    __syncthreads();
    // stage W2 chunk: 304 rows x 32 k x2 planes = 2432 x 16B
#pragma unroll
    for (int j = 0; j < 10; ++j) {
      int idx = t + j * 256;
      if (idx < 2432) {
        bool lo = idx >= 1216;
        int e = lo ? idx - 1216 : idx;
        int n = e >> 2, part = e & 3;
        const _Float16* src = wsp + (lo ? W2LO : W2HI) + n * K2P + kc * 32 + part * 8;
        _Float16* dst = (lo ? Wlo : Whi) + n * 32 + part * 8;
        *(half8*)dst = *(const half8*)src;
      }
    }
    __syncthreads();
    const int k0 = kc * 32 + q * 8;
    half8 ah, al;
    if (k0 + 8 <= 400) {
      ah = *(const half8*)(H1hi + (wave * 16 + m) * 400 + k0);
      al = *(const half8*)(H1lo + (wave * 16 + m) * 400 + k0);
    } else {
      ah = zf; al = zf;   // k 400..415 pad (kc==12, q>=2)
    }
#pragma unroll
    for (int nt = 0; nt < 19; ++nt) {
      const half8 bh = *(const half8*)(Whi + (nt * 16 + m) * 32 + q * 8);
      const half8 bl = *(const half8*)(Wlo + (nt * 16 + m) * 32 + q * 8);
      acc2[nt] = MFMA16(ah, bh, acc2[nt]);
      acc2[nt] = MFMA16(ah, bl, acc2[nt]);
      acc2[nt] = MFMA16(al, bh, acc2[nt]);
    }
  }
  __syncthreads();  // all h1 reads done -> safe to overlay h2 into same region
  _Float16* H2hi = (_Float16*)Hb;        // [64][320]
  _Float16* H2lo = H2hi + 64 * H2P;
  {
    // zero pad cols 304..319
    const int row = t >> 2, qq = t & 3;
#pragma unroll
    for (int j = 0; j < 4; ++j) {
      H2hi[row * H2P + 304 + qq * 4 + j] = (_Float16)0.f;
      H2lo[row * H2P + 304 + qq * 4 + j] = (_Float16)0.f;
    }
  }
#pragma unroll
  for (int nt = 0; nt < 19; ++nt) {
    const int col = nt * 16 + m;   // < 304
    const float bias = (col < H2D) ? b2[col] : 0.f;
#pragma unroll
    for (int r = 0; r < 4; ++r) {
      const int row = wave * 16 + q * 4 + r;
      float v = fmaxf(acc2[nt][r] + bias, 0.f);
      _Float16 hi = (_Float16)v;
      H2hi[row * H2P + col] = hi;
      H2lo[row * H2P + col] = (_Float16)(v - (float)hi);
    }
  }

  // ================= Layer 3: out3 = tanh(h2 @ W3 + b3) =================
  floatx4 acc3[16];
#pragma unroll
  for (int i = 0; i < 16; ++i) {
    acc3[i][0] = 0.f; acc3[i][1] = 0.f; acc3[i][2] = 0.f; acc3[i][3] = 0.f;
  }
  for (int kc = 0; kc < 10; ++kc) {
    __syncthreads();
    // stage W3 chunk: 256 rows x 32 k x2 planes = 2048 x 16B
#pragma unroll
    for (int j = 0; j < 8; ++j) {
      int idx = t + j * 256;
      if (idx < 2048) {
        bool lo = idx >= 1024;
        int e = lo ? idx - 1024 : idx;
        int n = e >> 2, part = e & 3;
        const _Float16* src = wsp + (lo ? W3LO : W3HI) + n * H2P + kc * 32 + part * 8;
        _Float16* dst = (lo ? Wlo : Whi) + n * 32 + part * 8;
        *(half8*)dst = *(const half8*)src;
      }
    }
    __syncthreads();
    const int k0 = kc * 32 + q * 8;
    const half8 ah = *(const half8*)(H2hi + (wave * 16 + m) * H2P + k0);
    const half8 al = *(const half8*)(H2lo + (wave * 16 + m) * H2P + k0);
#pragma unroll
    for (int nt = 0; nt < 16; ++nt) {
      const half8 bh = *(const half8*)(Whi + (nt * 16 + m) * 32 + q * 8);
      const half8 bl = *(const half8*)(Wlo + (nt * 16 + m) * 32 + q * 8);
      acc3[nt] = MFMA16(ah, bh, acc3[nt]);
      acc3[nt] = MFMA16(ah, bl, acc3[nt]);
      acc3[nt] = MFMA16(al, bh, acc3[nt]);
    }
  }
  __syncthreads();  // all h2 reads done -> overlay out3
  float* O3 = (float*)Hb;   // [64][256] fp32
#pragma unroll
  for (int nt = 0; nt < 16; ++nt) {
    const int col = nt * 16 + m;
    const float bias = (col < ODIM) ? b3[col] : 0.f;
#pragma unroll
    for (int r = 0; r < 4; ++r) {
      const int row = wave * 16 + q * 4 + r;
      O3[row * 256 + col] = tanhf(acc3[nt][r] + bias);
    }
  }
  __syncthreads();

  // ================= Epilogue: mixture stats, sample, logprobs =================
  {
    const int row = t >> 2, p = t & 3;   // 4 threads per batch row
    const long gr = rowbase + row;
    const float* Or = O3 + row * 256;
    float pc = 0.f, pt = 0.f, pe = 0.f;
    const int nact = (p == 0) ? 5 : 4;
    for (int ia = 0; ia < nact; ++ia) {
      const int a = p + ia * 4;          // p==0 also covers a=16
      float mw[5], mmv[5], lms[5];
#pragma unroll
      for (int j = 0; j < 5; ++j) {
        mw[j]  = Or[a * 5 + j];
        mmv[j] = Or[85 + a * 5 + j];
        lms[j] = Or[170 + a * 5 + j];
      }
      float w[5], es = 0.f;
#pragma unroll
      for (int j = 0; j < 5; ++j) { w[j] = expf(mw[j]); es += w[j]; }
      const float inv = 1.f / es;
      float mean = 0.f;
#pragma unroll
      for (int j = 0; j < 5; ++j) { w[j] *= inv; mean += w[j] * mmv[j]; }
      float alea = 0.f, epis = 0.f;
#pragma unroll
      for (int j = 0; j < 5; ++j) {
        float sd = expf(fminf(fmaxf(lms[j], -10.f), 2.f));
        alea += w[j] * sd;
        float d = mmv[j] - mean;
        epis += w[j] * d * d;
      }
      epis = fminf(fmaxf(epis, 4.53999297624848e-05f), 7.38905609893065f);
      const float total = alea + epis;
      const float ea = eps[gr * NACT + a];
      const float sample = mean + total * ea;
      const float ts = tanhf(sample);
      out[gr * NACT + a] = ts;
      pc += logf(1.f - ts * ts + 1e-6f);
      const float dz = sample - mean;
      const float zt = dz / total;
      const float ze = dz / epis;
      pt += zt * zt + 2.f * logf(total);
      pe += ze * ze + 2.f * logf(epis);
    }
    pc += __shfl_xor(pc, 1); pc += __shfl_xor(pc, 2);
    pt += __shfl_xor(pt, 1); pt += __shfl_xor(pt, 2);
    pe += __shfl_xor(pe, 1); pe += __shfl_xor(pe, 2);
    if (p == 0) {
      const float hdl2pi = 15.62195506447944f;  // 0.5*17*ln(2*pi)
      out[(long)NACT * BATCH + gr] = (-0.5f * pt - hdl2pi) - pc;
      out[(long)(NACT + 1) * BATCH + gr] = (-0.5f * pe - hdl2pi) - pc;
    }
  }
}

extern "C" void kernel_launch(void* const* d_in, const int* in_sizes, int n_in,
                              void* d_out, int out_size, void* d_ws, size_t ws_size,
                              hipStream_t stream) {
  const float* state = (const float*)d_in[0];
  const float* eps   = (const float*)d_in[1];
  const float* W1    = (const float*)d_in[2];
  const float* b1    = (const float*)d_in[3];
  const float* W2    = (const float*)d_in[4];
  const float* b2    = (const float*)d_in[5];
  const float* W3    = (const float*)d_in[6];
  const float* b3    = (const float*)d_in[7];
  float* out = (float*)d_out;
  _Float16* ws = (_Float16*)d_ws;

  (void)in_sizes; (void)n_in; (void)out_size; (void)ws_size;

  hipFuncSetAttribute(reinterpret_cast<const void*>(actor_kernel),
                      hipFuncAttributeMaxDynamicSharedMemorySize, 161792);

  prep_kernel<<<1414, 256, 0, stream>>>(W1, W2, W3, ws);
  actor_kernel<<<2048, 256, 161792, stream>>>(state, eps, b1, b2, b3, ws, out);
}

// Round 2
// 733.596 us; speedup vs baseline: 1.4425x; 1.4425x over previous
//
#include <hip/hip_runtime.h>

typedef _Float16 half8 __attribute__((ext_vector_type(8)));
typedef float floatx4 __attribute__((ext_vector_type(4)));

#define BATCH 131072
#define S_DIM 376
#define NACT 17

// padded weight plane geometry (transposed [n][k], zero-padded)
#define W1N 448
#define W1K 384
#define W2N 320
#define W2K 416
#define W3N 256
#define W3K 320

// ws offsets in halfs
#define W1HI 0
#define W1LO (W1N * W1K)                       // 172032
#define W2HI (2 * W1N * W1K)                   // 344064
#define W2LO (W2HI + W2N * W2K)                // 477184
#define W3HI (W2HI + 2 * W2N * W2K)            // 610304
#define W3LO (W3HI + W3N * W3K)                // 692224
#define WTOT (W3HI + 2 * W3N * W3K)            // 774144 halfs = 1.548 MB

#define MFMA16(a, b, c) __builtin_amdgcn_mfma_f32_16x16x32_f16(a, b, c, 0, 0, 0)

// ---------------- prep: split fp32 weights into (hi,lo) fp16 planes, transposed, padded ----------------
__global__ __launch_bounds__(256) void prep_kernel(const float* __restrict__ W1,
                                                   const float* __restrict__ W2,
                                                   const float* __restrict__ W3,
                                                   _Float16* __restrict__ ws) {
  int idx = blockIdx.x * 256 + threadIdx.x;
  float v;
  int hioff, looff;
  if (idx < W1N * W1K) {                        // [448][384]
    int n = idx / W1K, k = idx - n * W1K;
    v = (n < 400 && k < 376) ? W1[k * 400 + n] : 0.f;
    hioff = W1HI + idx; looff = W1LO + idx;
  } else if (idx < W1N * W1K + W2N * W2K) {     // [320][416]
    int e = idx - W1N * W1K;
    int n = e / W2K, k = e - n * W2K;
    v = (n < 300 && k < 400) ? W2[k * 300 + n] : 0.f;
    hioff = W2HI + e; looff = W2LO + e;
  } else if (idx < W1N * W1K + W2N * W2K + W3N * W3K) {  // [256][320]
    int e = idx - W1N * W1K - W2N * W2K;
    int n = e / W3K, k = e - n * W3K;
    v = (n < 255 && k < 300) ? W3[k * 255 + n] : 0.f;
    hioff = W3HI + e; looff = W3LO + e;
  } else {
    return;
  }
  _Float16 hi = (_Float16)v;
  ws[hioff] = hi;
  ws[looff] = (_Float16)(v - (float)hi);
}

// ---------------- barrier-free K-loop GEMM body ----------------
// A (hi/lo split planes) from LDS, stride AW halfs; B (hi/lo planes) direct from
// global ws, stride KP halfs. Wave handles NT column tiles x 4 row tiles (64 rows).
// No __syncthreads inside: compiler pipelines ds_read / global_load freely.
template <int NT, int CHUNKS, int AW, int KP>
__device__ __forceinline__ void gemm_layer(const _Float16* __restrict__ Ahi,
                                           const _Float16* __restrict__ Alo,
                                           const _Float16* __restrict__ Bhi,
                                           const _Float16* __restrict__ Blo,
                                           int ntm,  // ntBase*16 + m
                                           int q, int m, floatx4 (&acc)[4][NT]) {
  const int kq = q * 8;
  for (int kc = 0; kc < CHUNKS; ++kc) {
    const int ak = kc * 32 + kq;
    half8 ah[4], al[4];
#pragma unroll
    for (int mt = 0; mt < 4; ++mt) {
      ah[mt] = *(const half8*)(Ahi + (mt * 16 + m) * AW + ak);
      al[mt] = *(const half8*)(Alo + (mt * 16 + m) * AW + ak);
    }
    const _Float16* bbase = Bhi + ntm * KP + ak;
    const _Float16* lbase = Blo + ntm * KP + ak;
    half8 bh = *(const half8*)bbase;
    half8 bl = *(const half8*)lbase;
#pragma unroll
    for (int nt = 0; nt < NT; ++nt) {
      half8 nbh, nbl;
      if (nt + 1 < NT) {                         // 1-deep B prefetch
        nbh = *(const half8*)(bbase + (nt + 1) * 16 * KP);
        nbl = *(const half8*)(lbase + (nt + 1) * 16 * KP);
      }
#pragma unroll
      for (int mt = 0; mt < 4; ++mt) {
        acc[mt][nt] = MFMA16(ah[mt], bh, acc[mt][nt]);
        acc[mt][nt] = MFMA16(ah[mt], bl, acc[mt][nt]);
        acc[mt][nt] = MFMA16(al[mt], bh, acc[mt][nt]);
      }
      bh = nbh; bl = nbl;
    }
  }
}

// ---------------- fused actor kernel ----------------
// Block: 256 thr / 4 waves / 64 batch rows. Waves split N (n_s=4): each wave owns
// all 64 rows x its column slice -> every B fragment read by exactly one wave ->
// B streams from global (L2-resident weights), LDS only holds A/h planes.
// LDS overlay: Astage[64][416]pair -> H1[64][416]pair -> H2[64][320]pair -> O3[64][256]f32.
__global__ __launch_bounds__(256, 1) void actor_kernel(const float* __restrict__ state,
                                                       const float* __restrict__ eps,
                                                       const float* __restrict__ b1,
                                                       const float* __restrict__ b2,
                                                       const float* __restrict__ b3,
                                                       const _Float16* __restrict__ wsp,
                                                       float* __restrict__ out) {
  extern __shared__ char smem[];
  _Float16* Ahi = (_Float16*)smem;               // [64][416]
  _Float16* Alo = Ahi + 64 * 416;

  const int t = threadIdx.x;
  const int wave = t >> 6;
  const int lane = t & 63;
  const int q = lane >> 4;
  const int m = lane & 15;
  const long rowbase = (long)blockIdx.x * 64;

  // ---- stage state chunk-pair into LDS once (split done once per block) ----
  {
    const int row = t >> 2, p = t & 3;
    const long gbase = (rowbase + row) * S_DIM;
    for (int c0 = 0; c0 < 12; ++c0) {
      const int col = c0 * 32 + p * 8;
      float v[8];
      if (col + 8 <= S_DIM) {
        const float4* sp = (const float4*)(state + gbase + col);
        float4 x0 = sp[0], x1 = sp[1];
        v[0] = x0.x; v[1] = x0.y; v[2] = x0.z; v[3] = x0.w;
        v[4] = x1.x; v[5] = x1.y; v[6] = x1.z; v[7] = x1.w;
      } else {
#pragma unroll
        for (int j = 0; j < 8; ++j) v[j] = 0.f;
      }
      half8 h, l;
#pragma unroll
      for (int j = 0; j < 8; ++j) {
        _Float16 hi = (_Float16)v[j];
        h[j] = hi;
        l[j] = (_Float16)(v[j] - (float)hi);
      }
      *(half8*)(Ahi + row * 416 + col) = h;
      *(half8*)(Alo + row * 416 + col) = l;
    }
  }
  __syncthreads();

  // ================= Layer 1 =================
  floatx4 acc1[4][7];
#pragma unroll
  for (int a = 0; a < 4; ++a)
#pragma unroll
    for (int b = 0; b < 7; ++b) { acc1[a][b][0] = 0.f; acc1[a][b][1] = 0.f; acc1[a][b][2] = 0.f; acc1[a][b][3] = 0.f; }
  gemm_layer<7, 12, 416, W1K>(Ahi, Alo, wsp + W1HI, wsp + W1LO, wave * 112 + m, q, m, acc1);

  __syncthreads();  // all A reads done -> overlay h1 into same region
  _Float16* H1hi = Ahi;   // [64][416]
  _Float16* H1lo = Alo;
#pragma unroll
  for (int nt = 0; nt < 7; ++nt) {
    const int tile = wave * 7 + nt;
    if (tile < 26) {                 // tile 25 writes the zero pad cols 400..415
      const int col = tile * 16 + m;
      const float bias = (col < 400) ? b1[col] : 0.f;
#pragma unroll
      for (int mt = 0; mt < 4; ++mt)
#pragma unroll
        for (int r = 0; r < 4; ++r) {
          const int row = mt * 16 + q * 4 + r;
          float v = fmaxf(acc1[mt][nt][r] + bias, 0.f);
          _Float16 hi = (_Float16)v;
          H1hi[row * 416 + col] = hi;
          H1lo[row * 416 + col] = (_Float16)(v - (float)hi);
        }
    }
  }
  __syncthreads();

  // ================= Layer 2 =================
  floatx4 acc2[4][5];
#pragma unroll
  for (int a = 0; a < 4; ++a)
#pragma unroll
    for (int b = 0; b < 5; ++b) { acc2[a][b][0] = 0.f; acc2[a][b][1] = 0.f; acc2[a][b][2] = 0.f; acc2[a][b][3] = 0.f; }
  gemm_layer<5, 13, 416, W2K>(H1hi, H1lo, wsp + W2HI, wsp + W2LO, wave * 80 + m, q, m, acc2);

  __syncthreads();  // all h1 reads done -> overlay h2
  _Float16* H2hi = (_Float16*)smem;  // [64][320]
  _Float16* H2lo = H2hi + 64 * 320;
#pragma unroll
  for (int nt = 0; nt < 5; ++nt) {
    const int col = (wave * 5 + nt) * 16 + m;   // < 320; cols >=300 get zeros (padded W2/b2)
    const float bias = (col < 300) ? b2[col] : 0.f;
#pragma unroll
    for (int mt = 0; mt < 4; ++mt)
#pragma unroll
      for (int r = 0; r < 4; ++r) {
        const int row = mt * 16 + q * 4 + r;
        float v = fmaxf(acc2[mt][nt][r] + bias, 0.f);
        _Float16 hi = (_Float16)v;
        H2hi[row * 320 + col] = hi;
        H2lo[row * 320 + col] = (_Float16)(v - (float)hi);
      }
  }
  __syncthreads();

  // ================= Layer 3 =================
  floatx4 acc3[4][4];
#pragma unroll
  for (int a = 0; a < 4; ++a)
#pragma unroll
    for (int b = 0; b < 4; ++b) { acc3[a][b][0] = 0.f; acc3[a][b][1] = 0.f; acc3[a][b][2] = 0.f; acc3[a][b][3] = 0.f; }
  gemm_layer<4, 10, 320, W3K>(H2hi, H2lo, wsp + W3HI, wsp + W3LO, wave * 64 + m, q, m, acc3);

  __syncthreads();  // all h2 reads done -> overlay O3
  float* O3 = (float*)smem;  // [64][256] fp32
#pragma unroll
  for (int nt = 0; nt < 4; ++nt) {
    const int col = (wave * 4 + nt) * 16 + m;
    const float bias = (col < 255) ? b3[col] : 0.f;
#pragma unroll
    for (int mt = 0; mt < 4; ++mt)
#pragma unroll
      for (int r = 0; r < 4; ++r) {
        const int row = mt * 16 + q * 4 + r;
        O3[row * 256 + col] = tanhf(acc3[mt][nt][r] + bias);
      }
  }
  __syncthreads();

  // ================= Epilogue: mixture stats, sample, logprobs =================
  {
    const int row = t >> 2, p = t & 3;   // 4 threads per batch row
    const long gr = rowbase + row;
    const float* Or = O3 + row * 256;
    float pc = 0.f, pt = 0.f, pe = 0.f;
    const int nact = (p == 0) ? 5 : 4;
    for (int ia = 0; ia < nact; ++ia) {
      const int a = p + ia * 4;          // p==0 also covers a=16
      float mw[5], mmv[5], lms[5];
#pragma unroll
      for (int j = 0; j < 5; ++j) {
        mw[j]  = Or[a * 5 + j];
        mmv[j] = Or[85 + a * 5 + j];
        lms[j] = Or[170 + a * 5 + j];
      }
      float w[5], es = 0.f;
#pragma unroll
      for (int j = 0; j < 5; ++j) { w[j] = expf(mw[j]); es += w[j]; }
      const float inv = 1.f / es;
      float mean = 0.f;
#pragma unroll
      for (int j = 0; j < 5; ++j) { w[j] *= inv; mean += w[j] * mmv[j]; }
      float alea = 0.f, epis = 0.f;
#pragma unroll
      for (int j = 0; j < 5; ++j) {
        float sd = expf(fminf(fmaxf(lms[j], -10.f), 2.f));
        alea += w[j] * sd;
        float d = mmv[j] - mean;
        epis += w[j] * d * d;
      }
      epis = fminf(fmaxf(epis, 4.53999297624848e-05f), 7.38905609893065f);
      const float total = alea + epis;
      const float ea = eps[gr * NACT + a];
      const float sample = mean + total * ea;
      const float ts = tanhf(sample);
      out[gr * NACT + a] = ts;
      pc += logf(1.f - ts * ts + 1e-6f);
      const float dz = sample - mean;
      const float zt = dz / total;
      const float ze = dz / epis;
      pt += zt * zt + 2.f * logf(total);
      pe += ze * ze + 2.f * logf(epis);
    }
    pc += __shfl_xor(pc, 1); pc += __shfl_xor(pc, 2);
    pt += __shfl_xor(pt, 1); pt += __shfl_xor(pt, 2);
    pe += __shfl_xor(pe, 1); pe += __shfl_xor(pe, 2);
    if (p == 0) {
      const float hdl2pi = 15.62195506447944f;  // 0.5*17*ln(2*pi)
      out[(long)NACT * BATCH + gr] = (-0.5f * pt - hdl2pi) - pc;
      out[(long)(NACT + 1) * BATCH + gr] = (-0.5f * pe - hdl2pi) - pc;
    }
  }
}

extern "C" void kernel_launch(void* const* d_in, const int* in_sizes, int n_in,
                              void* d_out, int out_size, void* d_ws, size_t ws_size,
                              hipStream_t stream) {
  const float* state = (const float*)d_in[0];
  const float* eps   = (const float*)d_in[1];
  const float* W1    = (const float*)d_in[2];
  const float* b1    = (const float*)d_in[3];
  const float* W2    = (const float*)d_in[4];
  const float* b2    = (const float*)d_in[5];
  const float* W3    = (const float*)d_in[6];
  const float* b3    = (const float*)d_in[7];
  float* out = (float*)d_out;
  _Float16* ws = (_Float16*)d_ws;

  (void)in_sizes; (void)n_in; (void)out_size; (void)ws_size;

  hipFuncSetAttribute(reinterpret_cast<const void*>(actor_kernel),
                      hipFuncAttributeMaxDynamicSharedMemorySize, 106496);

  prep_kernel<<<1512, 256, 0, stream>>>(W1, W2, W3, ws);
  actor_kernel<<<2048, 256, 106496, stream>>>(state, eps, b1, b2, b3, ws, out);
}